// Round 1
// baseline (1321.588 us; speedup 1.0000x reference)
//
#include <hip/hip_runtime.h>
#include <hip/hip_bf16.h>

// ---------------------------------------------------------------------------
// Fused persistent-kernel MLP: 10 x (Linear -> BatchNorm(train) -> tanh) +
// Linear -> sigmoid, B = 2^20 rows.
//
// Strategy: one persistent kernel, 1024 blocks x 256 threads, 4 rows/thread
// (exactly B rows). Activations (<=20 wide) live in registers for the whole
// net. Each BN layer needs a device-wide reduction -> one global barrier per
// BN layer (10 total), implemented with agent-scope atomics. Co-residency:
// __launch_bounds__(256,4) => <=128 VGPR => 4 blocks/CU x 256 CUs = 1024.
// Weights (~6KB) staged to LDS once, rows zero-padded to x4 for aligned
// float4 broadcast reads.
// ---------------------------------------------------------------------------

#define NBLK 1024
#define NTHR 256
#define RPT  4
#define BATCHN 1048576
#define NREP 32        // LDS stat replicas (stride 49 is odd -> bank bijection)
#define SSTR 49
#define GSLOTS 8       // global stat/barrier contention splitting
#define GSTR 48        // per-slot float stride: [0..23]=sum, [24..47]=sumsq

static_assert(NBLK * NTHR * RPT == BATCHN, "row coverage");

static constexpr int D_[12] = {64, 4, 20, 10, 10, 10, 10, 10, 5, 5, 5, 1};

static constexpr int pad4c(int x) { return (x + 3) & ~3; }
static constexpr int woffc(int l) {
    int o = 0;
    for (int k = 0; k < l; ++k) o += D_[k + 1] * pad4c(D_[k]);
    return o;
}
static constexpr int boffc(int l) {
    int o = 0;
    for (int k = 0; k < l; ++k) o += D_[k + 1];
    return o;
}
static constexpr int WTOT = woffc(11);  // 1164 floats (padded weights)
static constexpr int BTOT = boffc(11);  // 90 biases
static constexpr int GTOT = boffc(10);  // 89 BN gammas/betas

struct Params {
    const float* x;
    const float* W[11];
    const float* b[11];
    const float* g[10];
    const float* bt[10];
    float* out;
    float* gstats;   // [10][GSLOTS][GSTR]
    unsigned* bar;   // [10][GSLOTS]
};

__device__ __forceinline__ float fast_tanh(float x) {
    // tanh(x) = 1 - 2/(exp2(2*log2e*x)+1); exp2f -> v_exp_f32
    float e = exp2f(x * 2.8853900817779268f);
    return 1.0f - __fdividef(2.0f, e + 1.0f);
}

// ---- staging helpers -------------------------------------------------------
template <int L>
__device__ __forceinline__ void stageW(const Params& p, float* lW, int tid) {
    constexpr int DIN = D_[L], DOUT = D_[L + 1], PD = pad4c(DIN), WO = woffc(L);
    for (int i = tid; i < DOUT * DIN; i += NTHR) {
        int o = i / DIN;          // compile-time divisor -> mul/shift
        int c = i - o * DIN;
        lW[WO + o * PD + c] = p.W[L][i];
    }
}

template <int L>
__device__ __forceinline__ void stageB(const Params& p, float* lB, float* lG,
                                       float* lT, int tid) {
    constexpr int DOUT = D_[L + 1], BO = boffc(L);
    if (tid < DOUT) {
        lB[BO + tid] = p.b[L][tid];
        if (L < 10) {
            lG[BO + tid] = p.g[L][tid];
            lT[BO + tid] = p.bt[L][tid];
        }
    }
}

// ---- BN(batch stats) + tanh, with device-wide barrier ----------------------
template <int L, int DOUT>
__device__ __forceinline__ void bn_stats_tanh(const Params& p,
                                              float (&acc)[RPT][DOUT],
                                              float (&buf)[RPT][20],
                                              const float* lG, const float* lT,
                                              float* bsum, float* lsc, float* lsh,
                                              int tid, int bslot) {
    // guard reuse of bsum/lsc/lsh from previous layer
    __syncthreads();
    for (int i = tid; i < NREP * SSTR; i += NTHR) bsum[i] = 0.0f;
    __syncthreads();

    // per-thread 4-row sums -> replicated LDS accumulators (conflict-free)
    const int rep = (tid & 31) * SSTR;
#pragma unroll
    for (int d = 0; d < DOUT; ++d) {
        float a0 = acc[0][d], a1 = acc[1][d], a2 = acc[2][d], a3 = acc[3][d];
        float s = (a0 + a1) + (a2 + a3);
        float s2 = fmaf(a0, a0, fmaf(a1, a1, fmaf(a2, a2, a3 * a3)));
        atomicAdd(&bsum[rep + d], s);
        atomicAdd(&bsum[rep + 24 + d], s2);
    }
    __syncthreads();

    // fold replicas, one global atomic per block per feature (8-way slots)
    if (tid < 2 * DOUT) {
        const int idx = (tid < DOUT) ? tid : (24 + (tid - DOUT));
        float v = 0.0f;
        for (int r = 0; r < NREP; ++r) v += bsum[r * SSTR + idx];
        atomicAdd(&p.gstats[(L * GSLOTS + bslot) * GSTR + idx], v);
    }
    __syncthreads();

    // device-wide barrier: one arrival per block, 8-way split counters
    if (tid == 0) {
        __hip_atomic_fetch_add(&p.bar[L * GSLOTS + bslot], 1u,
                               __ATOMIC_RELEASE, __HIP_MEMORY_SCOPE_AGENT);
        unsigned tot = 0;
        do {
            tot = 0;
            for (int q = 0; q < GSLOTS; ++q)
                tot += __hip_atomic_load(&p.bar[L * GSLOTS + q],
                                         __ATOMIC_RELAXED, __HIP_MEMORY_SCOPE_AGENT);
            if (tot < NBLK) __builtin_amdgcn_s_sleep(2);
        } while (tot < NBLK);
    }
    __syncthreads();

    // every block computes scale/shift from global sums (agent atomic loads
    // read the coherent point -> no extra fence needed)
    if (tid < DOUT) {
        float s = 0.0f, s2 = 0.0f;
        for (int q = 0; q < GSLOTS; ++q) {
            s += __hip_atomic_load(&p.gstats[(L * GSLOTS + q) * GSTR + tid],
                                   __ATOMIC_RELAXED, __HIP_MEMORY_SCOPE_AGENT);
            s2 += __hip_atomic_load(&p.gstats[(L * GSLOTS + q) * GSTR + 24 + tid],
                                    __ATOMIC_RELAXED, __HIP_MEMORY_SCOPE_AGENT);
        }
        constexpr float inv = 1.0f / (float)BATCHN;
        float m = s * inv;
        float var = fmaxf(s2 * inv - m * m, 0.0f);
        float scv = lG[boffc(L) + tid] * rsqrtf(var + 1e-5f);
        lsc[tid] = scv;
        lsh[tid] = lT[boffc(L) + tid] - m * scv;
    }
    __syncthreads();

#pragma unroll
    for (int j = 0; j < RPT; ++j)
#pragma unroll
        for (int d = 0; d < DOUT; ++d)
            buf[j][d] = fast_tanh(fmaf(acc[j][d], lsc[d], lsh[d]));
}

// ---- generic hidden layer (L = 1..9): Linear from buf -> BN -> tanh --------
template <int L>
__device__ __forceinline__ void layer_bn(const Params& p, const float* lW,
                                         const float* lB, const float* lG,
                                         const float* lT, float* bsum,
                                         float* lsc, float* lsh,
                                         float (&buf)[RPT][20], int tid, int bslot) {
    constexpr int DIN = D_[L], DOUT = D_[L + 1];
    constexpr int PD = pad4c(DIN), WO = woffc(L), BO = boffc(L);
    float acc[RPT][DOUT];
#pragma unroll
    for (int j = 0; j < RPT; ++j)
#pragma unroll
        for (int o = 0; o < DOUT; ++o) acc[j][o] = lB[BO + o];

#pragma unroll
    for (int o = 0; o < DOUT; ++o) {
#pragma unroll
        for (int c = 0; c < PD / 4; ++c) {
            const float4 w = *(const float4*)&lW[WO + o * PD + c * 4];
#pragma unroll
            for (int j = 0; j < RPT; ++j) {
                acc[j][o] = fmaf(w.x, buf[j][c * 4 + 0],
                            fmaf(w.y, buf[j][c * 4 + 1],
                            fmaf(w.z, buf[j][c * 4 + 2],
                            fmaf(w.w, buf[j][c * 4 + 3], acc[j][o]))));
            }
        }
    }
    bn_stats_tanh<L, DOUT>(p, acc, buf, lG, lT, bsum, lsc, lsh, tid, bslot);
}

// ---------------------------------------------------------------------------
__global__ void __launch_bounds__(NTHR, 4) mlp_fused(Params p) {
    __shared__ __align__(16) float lW[WTOT];
    __shared__ float lB[BTOT];
    __shared__ float lG[GTOT];
    __shared__ float lT[GTOT];
    __shared__ float bsum[NREP * SSTR];
    __shared__ float lsc[24], lsh[24];

    const int tid = threadIdx.x;
    const int bslot = blockIdx.x & (GSLOTS - 1);

    // stage weights to LDS (zero first -> padded columns are 0)
    for (int i = tid; i < WTOT; i += NTHR) lW[i] = 0.0f;
    __syncthreads();
    stageW<0>(p, lW, tid);  stageW<1>(p, lW, tid);  stageW<2>(p, lW, tid);
    stageW<3>(p, lW, tid);  stageW<4>(p, lW, tid);  stageW<5>(p, lW, tid);
    stageW<6>(p, lW, tid);  stageW<7>(p, lW, tid);  stageW<8>(p, lW, tid);
    stageW<9>(p, lW, tid);  stageW<10>(p, lW, tid);
    stageB<0>(p, lB, lG, lT, tid);  stageB<1>(p, lB, lG, lT, tid);
    stageB<2>(p, lB, lG, lT, tid);  stageB<3>(p, lB, lG, lT, tid);
    stageB<4>(p, lB, lG, lT, tid);  stageB<5>(p, lB, lG, lT, tid);
    stageB<6>(p, lB, lG, lT, tid);  stageB<7>(p, lB, lG, lT, tid);
    stageB<8>(p, lB, lG, lT, tid);  stageB<9>(p, lB, lG, lT, tid);
    stageB<10>(p, lB, lG, lT, tid);
    __syncthreads();

    // rows handled by this thread: rowbase + j*NTHR  (coalesced)
    const int rowbase = blockIdx.x * (NTHR * RPT) + tid;

    float buf[RPT][20];

    // ---- layer 0: x(64) -> 4, streamed from HBM ----
    {
        float acc[RPT][4];
#pragma unroll
        for (int j = 0; j < RPT; ++j)
#pragma unroll
            for (int o = 0; o < 4; ++o) acc[j][o] = lB[boffc(0) + o];
#pragma unroll
        for (int c = 0; c < 16; ++c) {
            const float4 w0 = *(const float4*)&lW[woffc(0) + 0 * 64 + c * 4];
            const float4 w1 = *(const float4*)&lW[woffc(0) + 1 * 64 + c * 4];
            const float4 w2 = *(const float4*)&lW[woffc(0) + 2 * 64 + c * 4];
            const float4 w3 = *(const float4*)&lW[woffc(0) + 3 * 64 + c * 4];
#pragma unroll
            for (int j = 0; j < RPT; ++j) {
                const float4 xv = *(const float4*)(p.x + (size_t)(rowbase + j * NTHR) * 64 + c * 4);
                acc[j][0] = fmaf(w0.x, xv.x, fmaf(w0.y, xv.y, fmaf(w0.z, xv.z, fmaf(w0.w, xv.w, acc[j][0]))));
                acc[j][1] = fmaf(w1.x, xv.x, fmaf(w1.y, xv.y, fmaf(w1.z, xv.z, fmaf(w1.w, xv.w, acc[j][1]))));
                acc[j][2] = fmaf(w2.x, xv.x, fmaf(w2.y, xv.y, fmaf(w2.z, xv.z, fmaf(w2.w, xv.w, acc[j][2]))));
                acc[j][3] = fmaf(w3.x, xv.x, fmaf(w3.y, xv.y, fmaf(w3.z, xv.z, fmaf(w3.w, xv.w, acc[j][3]))));
            }
        }
        bn_stats_tanh<0, 4>(p, acc, buf, lG, lT, bsum, lsc, lsh, tid, bslot);
    }

    // ---- layers 1..9 ----
    layer_bn<1>(p, lW, lB, lG, lT, bsum, lsc, lsh, buf, tid, bslot);
    layer_bn<2>(p, lW, lB, lG, lT, bsum, lsc, lsh, buf, tid, bslot);
    layer_bn<3>(p, lW, lB, lG, lT, bsum, lsc, lsh, buf, tid, bslot);
    layer_bn<4>(p, lW, lB, lG, lT, bsum, lsc, lsh, buf, tid, bslot);
    layer_bn<5>(p, lW, lB, lG, lT, bsum, lsc, lsh, buf, tid, bslot);
    layer_bn<6>(p, lW, lB, lG, lT, bsum, lsc, lsh, buf, tid, bslot);
    layer_bn<7>(p, lW, lB, lG, lT, bsum, lsc, lsh, buf, tid, bslot);
    layer_bn<8>(p, lW, lB, lG, lT, bsum, lsc, lsh, buf, tid, bslot);
    layer_bn<9>(p, lW, lB, lG, lT, bsum, lsc, lsh, buf, tid, bslot);

    // ---- layer 10: 5 -> 1, sigmoid, store ----
    {
        constexpr int WO = woffc(10), BO = boffc(10);
#pragma unroll
        for (int j = 0; j < RPT; ++j) {
            float a = lB[BO];
#pragma unroll
            for (int i = 0; i < 8; ++i)   // padded to 8; pad weights are 0
                a = fmaf(lW[WO + i], buf[j][i], a);
            float e = exp2f(a * -1.4426950408889634f);
            p.out[rowbase + j * NTHR] = __fdividef(1.0f, 1.0f + e);
        }
    }
}

// zero the stats + barrier region each call (ws is NOT re-poisoned between
// graph replays, so this must run every launch)
__global__ void init_ws(float* gstats, unsigned* bar) {
    int i = threadIdx.x + blockIdx.x * blockDim.x;
    if (i < 10 * GSLOTS * GSTR) gstats[i] = 0.0f;
    if (i < 10 * GSLOTS) bar[i] = 0u;
}

extern "C" void kernel_launch(void* const* d_in, const int* in_sizes, int n_in,
                              void* d_out, int out_size, void* d_ws, size_t ws_size,
                              hipStream_t stream) {
    Params p;
    p.x = (const float*)d_in[0];
    int k = 1;
    for (int l = 0; l < 11; ++l) {
        p.W[l] = (const float*)d_in[k++];
        p.b[l] = (const float*)d_in[k++];
        if (l < 10) {
            p.g[l] = (const float*)d_in[k++];
            p.bt[l] = (const float*)d_in[k++];
        }
    }
    p.out = (float*)d_out;
    p.gstats = (float*)d_ws;
    p.bar = (unsigned*)((char*)d_ws + (size_t)(10 * GSLOTS * GSTR) * sizeof(float));

    init_ws<<<dim3((10 * GSLOTS * GSTR + 255) / 256), dim3(256), 0, stream>>>(p.gstats, p.bar);
    mlp_fused<<<dim3(NBLK), dim3(NTHR), 0, stream>>>(p);
}